// Round 8
// baseline (272.452 us; speedup 1.0000x reference)
//
#include <hip/hip_runtime.h>
#include <hip/hip_bf16.h>

// ---------------------------------------------------------------------------
// GATsmall: 2x GATConv (8 heads) + GCNConv head. N=50000, E=500000 (+N self
// loops). Round 8: agg inner loop restructured for latency-bound regime:
// lane owns 8 channels (uint4 16B gathers), EPS edge-slots in parallel per
// wave, per-lane exp for its own head (zero shfl in loop), unroll-4 MLP.
// Cross-slot reduce once per node. gcn dinv folded into gemm epilogue.
// bf16 MFMA GEMMs; fp32-factored attention logits; all tables bf16.
// ---------------------------------------------------------------------------

typedef __attribute__((ext_vector_type(8))) short bf16x8;
typedef __attribute__((ext_vector_type(4))) float f32x4;

// ---------------- CSR build ----------------

__global__ __launch_bounds__(256) void zero_deg_kernel(int* __restrict__ deg, int n) {
    int i = blockIdx.x * 256 + threadIdx.x;
    if (i < n) deg[i] = 0;
}

__global__ __launch_bounds__(256) void hist_kernel(const int* __restrict__ ei, int E, int Etot,
                                                   int* __restrict__ deg) {
    int e = blockIdx.x * 256 + threadIdx.x;
    if (e >= Etot) return;
    int d = (e < E) ? ei[E + e] : (e - E);  // tail = self loops
    atomicAdd(&deg[d], 1);
}

__global__ __launch_bounds__(256) void scanA_kernel(const int* __restrict__ deg,
                                                    int* __restrict__ off,
                                                    int* __restrict__ bsum, int n) {
    __shared__ int buf[256];
    int t = threadIdx.x;
    int i = blockIdx.x * 256 + t;
    int v = (i < n) ? deg[i] : 0;
    buf[t] = v;
    __syncthreads();
    #pragma unroll
    for (int st = 1; st < 256; st <<= 1) {
        int x = (t >= st) ? buf[t - st] : 0;
        __syncthreads();
        buf[t] += x;
        __syncthreads();
    }
    if (i < n) off[i + 1] = buf[t];
    if (t == 255) bsum[blockIdx.x] = buf[255];
}

__global__ __launch_bounds__(256) void scanB_kernel(int* __restrict__ bsum, int nb) {
    __shared__ int buf[256];
    int t = threadIdx.x;
    int v = (t < nb) ? bsum[t] : 0;
    buf[t] = v;
    __syncthreads();
    #pragma unroll
    for (int st = 1; st < 256; st <<= 1) {
        int x = (t >= st) ? buf[t - st] : 0;
        __syncthreads();
        buf[t] += x;
        __syncthreads();
    }
    if (t < nb) bsum[t] = buf[t] - v;  // exclusive prefix of chunk sums
}

__global__ __launch_bounds__(256) void scanC_kernel(const int* __restrict__ deg,
                                                    int* __restrict__ off,
                                                    const int* __restrict__ bsum,
                                                    int* __restrict__ cur,
                                                    float* __restrict__ dinv, int n) {
    int i = blockIdx.x * 256 + threadIdx.x;
    if (i < n) {
        int o = off[i + 1] + bsum[blockIdx.x];
        off[i + 1] = o;
        cur[i] = o - deg[i];
        dinv[i] = rsqrtf((float)deg[i]);  // deg >= 1 (self loop)
    }
    if (i == 0) off[0] = 0;
}

__global__ __launch_bounds__(256) void scatter_kernel(const int* __restrict__ ei, int E, int Etot,
                                                      int* __restrict__ cur,
                                                      int* __restrict__ ssrc) {
    int e = blockIdx.x * 256 + threadIdx.x;
    if (e >= Etot) return;
    int s, d;
    if (e < E) { s = ei[e]; d = ei[E + e]; }
    else       { s = e - E; d = e - E; }
    int pos = atomicAdd(&cur[d], 1);
    ssrc[pos] = s;
}

// ---------------- helpers ----------------

__device__ __forceinline__ float4 bf4_to_f4(uint2 v) {
    float4 r;
    r.x = __uint_as_float((v.x & 0xFFFFu) << 16);
    r.y = __uint_as_float(v.x & 0xFFFF0000u);
    r.z = __uint_as_float((v.y & 0xFFFFu) << 16);
    r.w = __uint_as_float(v.y & 0xFFFF0000u);
    return r;
}

__global__ __launch_bounds__(256) void cvt_bf16_kernel(const float* __restrict__ in,
                                                       ushort* __restrict__ outb, int count) {
    int i = (blockIdx.x * 256 + threadIdx.x) * 4;
    if (i >= count) return;
    float4 v = *reinterpret_cast<const float4*>(in + i);
    ushort4 u;
    __hip_bfloat16 b0 = __float2bfloat16(v.x); u.x = *reinterpret_cast<ushort*>(&b0);
    __hip_bfloat16 b1 = __float2bfloat16(v.y); u.y = *reinterpret_cast<ushort*>(&b1);
    __hip_bfloat16 b2 = __float2bfloat16(v.z); u.z = *reinterpret_cast<ushort*>(&b2);
    __hip_bfloat16 b3 = __float2bfloat16(v.w); u.w = *reinterpret_cast<ushort*>(&b3);
    *reinterpret_cast<ushort4*>(outb + i) = u;
}

// W [K][NC] fp32 -> Wt [NC][K] bf16
template <int K, int NC>
__global__ __launch_bounds__(256) void wtrans_kernel(const float* __restrict__ W,
                                                     ushort* __restrict__ Wt) {
    int t = blockIdx.x * 256 + threadIdx.x;  // t = nidx*K + k
    if (t >= K * NC) return;
    int nn = t / K, k = t % K;
    __hip_bfloat16 b = __float2bfloat16(W[(size_t)k * NC + nn]);
    Wt[t] = *reinterpret_cast<ushort*>(&b);
}

// ---------------- factored attention weights: w[k][h] = W[k,:] . att[h] -----

template <int K, int D>
__global__ __launch_bounds__(256) void wprep_kernel(const float* __restrict__ W,
                                                    const float* __restrict__ att_s,
                                                    const float* __restrict__ att_d,
                                                    float* __restrict__ ws,
                                                    float* __restrict__ wd) {
    int t = blockIdx.x * 256 + threadIdx.x;  // t = k*8 + h
    if (t >= K * 8) return;
    int k = t >> 3, h = t & 7;
    const float* wrow = W + (size_t)k * (8 * D) + h * D;
    const float* as = att_s + h * D;
    const float* ad = att_d + h * D;
    float s1 = 0.f, s2 = 0.f;
    #pragma unroll
    for (int d = 0; d < D; d += 4) {
        float4 wv = *reinterpret_cast<const float4*>(wrow + d);
        float4 av = *reinterpret_cast<const float4*>(as + d);
        float4 dv = *reinterpret_cast<const float4*>(ad + d);
        s1 += wv.x * av.x + wv.y * av.y + wv.z * av.z + wv.w * av.w;
        s2 += wv.x * dv.x + wv.y * dv.y + wv.z * dv.z + wv.w * dv.w;
    }
    ws[t] = s1;
    wd[t] = s2;
}

// a_s[n][8], a_d[n][8] = Xb[n,K](bf16) @ ws/wd[K,8] (fp32 accumulate)
template <int K>
__global__ __launch_bounds__(256) void adots_kernel(const ushort* __restrict__ Xb,
                                                    const float* __restrict__ ws,
                                                    const float* __restrict__ wd,
                                                    float* __restrict__ a_s,
                                                    float* __restrict__ a_d, int n) {
    int gid = blockIdx.x * 256 + threadIdx.x;
    if (gid >= n * 8) return;
    int node = gid >> 3, h = gid & 7;
    const ushort* xp = Xb + (size_t)node * K;
    float s1 = 0.f, s2 = 0.f;
    #pragma unroll 4
    for (int k = 0; k < K; k += 8) {
        uint4 v = *reinterpret_cast<const uint4*>(xp + k);
        float4 x0 = bf4_to_f4(make_uint2(v.x, v.y));
        float4 x1 = bf4_to_f4(make_uint2(v.z, v.w));
        s1 += x0.x * ws[(k + 0) * 8 + h] + x0.y * ws[(k + 1) * 8 + h] +
              x0.z * ws[(k + 2) * 8 + h] + x0.w * ws[(k + 3) * 8 + h] +
              x1.x * ws[(k + 4) * 8 + h] + x1.y * ws[(k + 5) * 8 + h] +
              x1.z * ws[(k + 6) * 8 + h] + x1.w * ws[(k + 7) * 8 + h];
        s2 += x0.x * wd[(k + 0) * 8 + h] + x0.y * wd[(k + 1) * 8 + h] +
              x0.z * wd[(k + 2) * 8 + h] + x0.w * wd[(k + 3) * 8 + h] +
              x1.x * wd[(k + 4) * 8 + h] + x1.y * wd[(k + 5) * 8 + h] +
              x1.z * wd[(k + 6) * 8 + h] + x1.w * wd[(k + 7) * 8 + h];
    }
    a_s[gid] = s1;
    a_d[gid] = s2;
}

// ---------------- bf16 MFMA GEMM: Cb[M,NC] = Ab[M,K] @ Bt[NC,K]^T -----------

template <int K, int NC, int BN>
__global__ __launch_bounds__(256) void mfma_gemm_kernel(const ushort* __restrict__ Ab,
                                                        const ushort* __restrict__ Bt,
                                                        ushort* __restrict__ Cb, int M) {
    constexpr int BM = 128, BK = 32;
    constexpr int FN = BN / 32;
    __shared__ ushort As[BM * BK];
    __shared__ ushort Bs[BN * BK];
    const int tid = threadIdx.x;
    const int lane = tid & 63;
    const int wid = tid >> 6;
    const int bm = blockIdx.y * BM;
    const int bn = blockIdx.x * BN;
    const int wm = (wid >> 1) * 64;
    const int wn = (wid & 1) * (BN / 2);
    const int l15 = lane & 15;
    const int l4 = lane >> 4;
    f32x4 zero4 = {0.f, 0.f, 0.f, 0.f};
    f32x4 acc[4][FN];
    #pragma unroll
    for (int i = 0; i < 4; ++i)
        #pragma unroll
        for (int j = 0; j < FN; ++j) acc[i][j] = zero4;

    for (int k0 = 0; k0 < K; k0 += BK) {
        #pragma unroll
        for (int p = 0; p < 2; ++p) {
            int ci = tid + p * 256;
            int r = ci >> 2, c = ci & 3;
            int row = bm + r;
            uint4 v = make_uint4(0, 0, 0, 0);
            if (row < M) v = *reinterpret_cast<const uint4*>(&Ab[(size_t)row * K + k0 + c * 8]);
            *reinterpret_cast<uint4*>(&As[r * BK + c * 8]) = v;
        }
        #pragma unroll
        for (int p = 0; p < BN / 64; ++p) {
            int ci = tid + p * 256;
            int r = ci >> 2, c = ci & 3;
            uint4 v = *reinterpret_cast<const uint4*>(&Bt[(size_t)(bn + r) * K + k0 + c * 8]);
            *reinterpret_cast<uint4*>(&Bs[r * BK + c * 8]) = v;
        }
        __syncthreads();
        bf16x8 af[4], bfr[FN];
        #pragma unroll
        for (int i = 0; i < 4; ++i)
            af[i] = *reinterpret_cast<const bf16x8*>(&As[(wm + 16 * i + l15) * BK + l4 * 8]);
        #pragma unroll
        for (int j = 0; j < FN; ++j)
            bfr[j] = *reinterpret_cast<const bf16x8*>(&Bs[(wn + 16 * j + l15) * BK + l4 * 8]);
        #pragma unroll
        for (int i = 0; i < 4; ++i)
            #pragma unroll
            for (int j = 0; j < FN; ++j)
                acc[i][j] = __builtin_amdgcn_mfma_f32_16x16x32_bf16(af[i], bfr[j], acc[i][j], 0, 0, 0);
        __syncthreads();
    }
    #pragma unroll
    for (int i = 0; i < 4; ++i) {
        #pragma unroll
        for (int p = 0; p < 4; ++p) {
            int row = bm + wm + 16 * i + l4 * 4 + p;
            if (row < M) {
                #pragma unroll
                for (int j = 0; j < FN; ++j) {
                    __hip_bfloat16 hb = __float2bfloat16(acc[i][j][p]);
                    Cb[(size_t)row * NC + bn + wn + 16 * j + l15] = *reinterpret_cast<ushort*>(&hb);
                }
            }
        }
    }
}

// ---------------- fused GAT aggregation (softmax + bf16 gather) -------------
// One wave per node. Lane owns 8 channels (uint4 16B gather); LR = C/8 lanes
// cover a row; EPS = 64/LR edge-slots process EPS edges concurrently. Each
// lane computes exp(lrelu(.)) for its own (edge-slot, head) — no shfl in the
// loop; ssrc/a_src loads are group-uniform (coalesced broadcast). Cross-slot
// reduce once per node via shfl_xor. Sum(ev*h)/(Sum(ev)+eps) == reference.

#define LRELU_EXP(e) __expf((e) > 0.f ? (e) : 0.2f * (e))

template <int C, int DH>
__global__ __launch_bounds__(256) void gat_agg_kernel(const ushort* __restrict__ hfeat,
                                                      const float* __restrict__ a_src,
                                                      const float* __restrict__ a_dst,
                                                      const int* __restrict__ off,
                                                      const int* __restrict__ ssrc,
                                                      const float* __restrict__ bias,
                                                      ushort* __restrict__ outb, int n) {
    constexpr int LR = C / 8;    // lanes per row: 32 (L1), 16 (L2)
    constexpr int EPS = 64 / LR; // edge slots:     2 (L1),  4 (L2)
    const int node = blockIdx.x * 4 + (threadIdx.x >> 6);
    if (node >= n) return;
    const int lane = threadIdx.x & 63;
    const int lir = lane & (LR - 1);
    const int es = lane / LR;
    const int c0 = lir * 8;
    const int h = c0 / DH;
    const float adst = a_dst[node * 8 + h];
    const int o0 = off[node], o1 = off[node + 1];
    float a0 = 0.f, a1 = 0.f, a2 = 0.f, a3 = 0.f;
    float a4 = 0.f, a5 = 0.f, a6 = 0.f, a7 = 0.f, ssum = 0.f;
    #pragma unroll 4
    for (int i = o0; i < o1; i += EPS) {
        int idx = i + es;
        bool ok = idx < o1;
        int s = ssrc[ok ? idx : (o1 - 1)];
        float e = a_src[s * 8 + h] + adst;
        float ev = ok ? LRELU_EXP(e) : 0.f;
        uint4 rv = *reinterpret_cast<const uint4*>(&hfeat[(size_t)s * C + c0]);
        float4 x0 = bf4_to_f4(make_uint2(rv.x, rv.y));
        float4 x1 = bf4_to_f4(make_uint2(rv.z, rv.w));
        ssum += ev;
        a0 += ev * x0.x; a1 += ev * x0.y; a2 += ev * x0.z; a3 += ev * x0.w;
        a4 += ev * x1.x; a5 += ev * x1.y; a6 += ev * x1.z; a7 += ev * x1.w;
    }
    // reduce across edge slots (lanes offset by multiples of LR)
    #pragma unroll
    for (int m = LR; m < 64; m <<= 1) {
        ssum += __shfl_xor(ssum, m);
        a0 += __shfl_xor(a0, m); a1 += __shfl_xor(a1, m);
        a2 += __shfl_xor(a2, m); a3 += __shfl_xor(a3, m);
        a4 += __shfl_xor(a4, m); a5 += __shfl_xor(a5, m);
        a6 += __shfl_xor(a6, m); a7 += __shfl_xor(a7, m);
    }
    if (es == 0) {
        float sinv = 1.f / (ssum + 1e-16f);
        float4 bb0 = *reinterpret_cast<const float4*>(bias + c0);
        float4 bb1 = *reinterpret_cast<const float4*>(bias + c0 + 4);
        float o[8];
        o[0] = fmaxf(a0 * sinv + bb0.x, 0.f); o[1] = fmaxf(a1 * sinv + bb0.y, 0.f);
        o[2] = fmaxf(a2 * sinv + bb0.z, 0.f); o[3] = fmaxf(a3 * sinv + bb0.w, 0.f);
        o[4] = fmaxf(a4 * sinv + bb1.x, 0.f); o[5] = fmaxf(a5 * sinv + bb1.y, 0.f);
        o[6] = fmaxf(a6 * sinv + bb1.z, 0.f); o[7] = fmaxf(a7 * sinv + bb1.w, 0.f);
        ushort u[8];
        #pragma unroll
        for (int j = 0; j < 8; ++j) {
            __hip_bfloat16 hb = __float2bfloat16(o[j]);
            u[j] = *reinterpret_cast<ushort*>(&hb);
        }
        *reinterpret_cast<uint4*>(&outb[(size_t)node * C + c0]) = *reinterpret_cast<uint4*>(u);
    }
}

// ---------------- GCN head ----------------

// g[node][c] = (out2b[node,:] @ Wg[:,c]) * dinv[node]   (dinv pre-folded)
__global__ __launch_bounds__(256) void gcn_gemm_kernel(const ushort* __restrict__ Ab,
                                                       const float* __restrict__ Wg,
                                                       const float* __restrict__ dinv,
                                                       float* __restrict__ g, int n) {
    __shared__ float W[128 * 8];
    for (int i = threadIdx.x; i < 1024; i += 256) W[i] = Wg[i];
    __syncthreads();
    int gid = blockIdx.x * 256 + threadIdx.x;
    if (gid >= n * 8) return;
    int node = gid >> 3, c = gid & 7;
    const ushort* ap = Ab + (size_t)node * 128;
    float acc = 0.f;
    #pragma unroll
    for (int k = 0; k < 128; k += 8) {
        uint4 v = *reinterpret_cast<const uint4*>(ap + k);
        float4 x0 = bf4_to_f4(make_uint2(v.x, v.y));
        float4 x1 = bf4_to_f4(make_uint2(v.z, v.w));
        acc += x0.x * W[(k + 0) * 8 + c] + x0.y * W[(k + 1) * 8 + c] +
               x0.z * W[(k + 2) * 8 + c] + x0.w * W[(k + 3) * 8 + c] +
               x1.x * W[(k + 4) * 8 + c] + x1.y * W[(k + 5) * 8 + c] +
               x1.z * W[(k + 6) * 8 + c] + x1.w * W[(k + 7) * 8 + c];
    }
    g[gid] = acc * dinv[node];
}

__global__ __launch_bounds__(256) void gcn_agg_kernel(const float* __restrict__ g,
                                                      const float* __restrict__ dinv,
                                                      const int* __restrict__ off,
                                                      const int* __restrict__ ssrc,
                                                      const float* __restrict__ bg,
                                                      float* __restrict__ outp, int n) {
    int gid = blockIdx.x * 256 + threadIdx.x;
    if (gid >= n * 8) return;
    int node = gid >> 3, c = gid & 7;
    int o0 = off[node], o1 = off[node + 1];
    float acc = 0.f;
    for (int i = o0; i < o1; ++i) {
        int s = ssrc[i];
        acc += g[(size_t)s * 8 + c];   // dinv[s] already folded in
    }
    outp[gid] = acc * dinv[node] + bg[c];
}

// ---------------- launch ----------------

extern "C" void kernel_launch(void* const* d_in, const int* in_sizes, int n_in,
                              void* d_out, int out_size, void* d_ws, size_t ws_size,
                              hipStream_t stream) {
    const float* x      = (const float*)d_in[0];
    const int*   ei     = (const int*)d_in[1];
    const float* W1     = (const float*)d_in[2];
    const float* att_s1 = (const float*)d_in[3];
    const float* att_d1 = (const float*)d_in[4];
    const float* b1     = (const float*)d_in[5];
    const float* W2     = (const float*)d_in[6];
    const float* att_s2 = (const float*)d_in[7];
    const float* att_d2 = (const float*)d_in[8];
    const float* b2     = (const float*)d_in[9];
    const float* Wg     = (const float*)d_in[10];
    const float* bg     = (const float*)d_in[11];
    float* out = (float*)d_out;

    const int n    = in_sizes[0] / 128;  // 50000
    const int E    = in_sizes[1] / 2;    // 500000
    const int Etot = E + n;              // 550000

    // workspace carve-up (~70 MB), with region reuse:
    //   regA: h1b bf16 [n,256]  -> out2b bf16 [n,128] (h1b dead after agg1)
    //   regC: xb  bf16 [n,128]  -> h2b  bf16 [n,128]  (xb dead after gemm1)
    float*  wsp   = (float*)d_ws;
    float*  regA  = wsp;                              // [n*128] floats
    float*  regB  = regA + (size_t)n * 128;           // [n*128]: out1b bf16 [n,256]
    float*  regC  = regB + (size_t)n * 128;           // [n*64]
    float*  a_s   = regC + (size_t)n * 64;            // [n*8]
    float*  a_d   = a_s + (size_t)n * 8;              // [n*8]
    float*  g     = a_d + (size_t)n * 8;              // [n*8]
    float*  dinv  = g + (size_t)n * 8;                // [n]
    float*  w1s   = dinv + n;                         // [1024]
    float*  w1d   = w1s + 1024;                       // [1024]
    float*  w2s   = w1d + 1024;                       // [2048]
    float*  w2d   = w2s + 2048;                       // [2048]
    float*  w1t_f = w2d + 2048;                       // W1t bf16 [256][128]
    float*  w2t_f = w1t_f + 16384;                    // W2t bf16 [128][256]
    int*    off   = (int*)(w2t_f + 16384);            // [n+1]
    int*    deg   = off + (n + 1);                    // [n]
    int*    cur   = deg + n;                          // [n]
    int*    ssrc  = cur + n;                          // [Etot]
    int*    bsum  = ssrc + Etot;                      // [<=256]

    ushort* h1b   = (ushort*)regA;
    ushort* out2b = (ushort*)regA;
    ushort* out1b = (ushort*)regB;
    ushort* xb    = (ushort*)regC;
    ushort* h2b   = (ushort*)regC;
    ushort* W1t   = (ushort*)w1t_f;
    ushort* W2t   = (ushort*)w2t_f;

    const dim3 b256(256);
    const int nch = (n + 255) / 256;

    // CSR build
    zero_deg_kernel<<<nch, b256, 0, stream>>>(deg, n);
    hist_kernel<<<(Etot + 255) / 256, b256, 0, stream>>>(ei, E, Etot, deg);
    scanA_kernel<<<nch, b256, 0, stream>>>(deg, off, bsum, n);
    scanB_kernel<<<1, b256, 0, stream>>>(bsum, nch);
    scanC_kernel<<<nch, b256, 0, stream>>>(deg, off, bsum, cur, dinv, n);
    scatter_kernel<<<(Etot + 255) / 256, b256, 0, stream>>>(ei, E, Etot, cur, ssrc);

    // tiny preps: factored attn weights, bf16 input/weight copies
    wprep_kernel<128, 32><<<4, b256, 0, stream>>>(W1, att_s1, att_d1, w1s, w1d);
    wprep_kernel<256, 16><<<8, b256, 0, stream>>>(W2, att_s2, att_d2, w2s, w2d);
    cvt_bf16_kernel<<<(n * 128 / 4 + 255) / 256, b256, 0, stream>>>(x, xb, n * 128);
    wtrans_kernel<128, 256><<<(32768 + 255) / 256, b256, 0, stream>>>(W1, W1t);
    wtrans_kernel<256, 128><<<(32768 + 255) / 256, b256, 0, stream>>>(W2, W2t);

    // layer 1: GAT(128 -> 8x32)
    adots_kernel<128><<<(n * 8 + 255) / 256, b256, 0, stream>>>(xb, w1s, w1d, a_s, a_d, n);
    mfma_gemm_kernel<128, 256, 128><<<dim3(2, (n + 127) / 128), b256, 0, stream>>>(xb, W1t, h1b, n);
    gat_agg_kernel<256, 32><<<(n + 3) / 4, b256, 0, stream>>>(h1b, a_s, a_d, off, ssrc, b1, out1b, n);

    // layer 2: GAT(256 -> 8x16)
    adots_kernel<256><<<(n * 8 + 255) / 256, b256, 0, stream>>>(out1b, w2s, w2d, a_s, a_d, n);
    mfma_gemm_kernel<256, 128, 64><<<dim3(2, (n + 127) / 128), b256, 0, stream>>>(out1b, W2t, h2b, n);
    gat_agg_kernel<128, 16><<<(n + 3) / 4, b256, 0, stream>>>(h2b, a_s, a_d, off, ssrc, b2, out2b, n);

    // GCN head
    gcn_gemm_kernel<<<(n * 8 + 255) / 256, b256, 0, stream>>>(out2b, Wg, dinv, g, n);
    gcn_agg_kernel<<<(n * 8 + 255) / 256, b256, 0, stream>>>(g, dinv, off, ssrc, bg, out, n);
}